// Round 6
// baseline (212.878 us; speedup 1.0000x reference)
//
#include <hip/hip_runtime.h>

// LSTM forecast: B=1024, S=512, I=1, H=50.
// 1 wave = 1 batch (1024 waves = 1/SIMD chip-wide). Lane j<50 owns the 4
// gate rows for hidden index j; cell update lane-local; h broadcast via LDS.
// R6: matmul as 100 x v_pk_fma_f32 (inline asm, 2 f32 MACs/instr) on f32x2
// weight pairs (200 VGPRs). Register budget unlocked with
// amdgpu_flat_work_group_size + amdgpu_waves_per_eu(1,1) (R5 showed the
// allocator capping at 132 VGPRs and spilling the pinned weights).

typedef float f32x2 __attribute__((ext_vector_type(2)));

#define LOG2E 1.44269504088896340736f
#define B_ 1024
#define S_ 512
#define H_ 50

__device__ __forceinline__ float rcp_(float x) { return __builtin_amdgcn_rcpf(x); }
__device__ __forceinline__ float ex2_(float x) { return __builtin_amdgcn_exp2f(x); }

// Pack W_hh (f32, activation log2-scales folded in) into [gate][pair][lane]
// f32x2 so lane j loads coalesced pairs (w[g][j][2m], w[g][j][2m+1]).
__global__ void lstm_pack(const float* __restrict__ W_ih, const float* __restrict__ W_hh,
                          const float* __restrict__ b_ih, const float* __restrict__ b_hh,
                          f32x2* __restrict__ wf2, float* __restrict__ wih_pk,
                          float* __restrict__ bias_pk)
{
    int tid = blockIdx.x * blockDim.x + threadIdx.x;
    int stride = blockDim.x * gridDim.x;
    for (int p = tid; p < 4 * 25 * 64; p += stride) {
        int j = p & 63;
        int m = (p >> 6) % 25;
        int g = p / (25 * 64);
        float s = (g == 2) ? (2.0f * LOG2E) : (-LOG2E);
        f32x2 v; v.x = 0.0f; v.y = 0.0f;
        if (j < H_) {
            const float* row = &W_hh[(g * H_ + j) * H_];
            v.x = s * row[2 * m];
            v.y = s * row[2 * m + 1];
        }
        wf2[p] = v;
    }
    for (int p = tid; p < 4 * 64; p += stride) {
        int j = p & 63;
        int g = p >> 6;
        float s = (g == 2) ? (2.0f * LOG2E) : (-LOG2E);
        float wi = 0.0f, bb = 0.0f;
        if (j < H_) {
            int row = g * H_ + j;
            wi = s * W_ih[row];
            bb = s * (b_ih[row] + b_hh[row]);
        }
        wih_pk[p] = wi;
        bias_pk[p] = bb;
    }
}

__global__
__attribute__((amdgpu_flat_work_group_size(64, 64)))
__attribute__((amdgpu_waves_per_eu(1, 1)))
void lstm_main(const float* __restrict__ x, const float* __restrict__ h0,
               const float* __restrict__ c0, const float* __restrict__ fc_w,
               const float* __restrict__ fc_b, const f32x2* __restrict__ wf2,
               const float* __restrict__ wih_pk, const float* __restrict__ bias_pk,
               float* __restrict__ out)
{
    const int b = blockIdx.x;
    const int j = threadIdx.x;

    __shared__ float hs[64];

    // Per-lane weights: 4 gates x 25 f32x2 = 200 VGPRs. Pinned (R3/R4 lesson:
    // prevents in-loop rematerialization).
    f32x2 w0[25], w1[25], w2[25], w3[25];
    #pragma unroll
    for (int m = 0; m < 25; ++m) {
        w0[m] = wf2[(0 * 25 + m) * 64 + j];
        w1[m] = wf2[(1 * 25 + m) * 64 + j];
        w2[m] = wf2[(2 * 25 + m) * 64 + j];
        w3[m] = wf2[(3 * 25 + m) * 64 + j];
    }
    #pragma unroll
    for (int m = 0; m < 25; ++m) {
        asm("" : "+v"(w0[m]));
        asm("" : "+v"(w1[m]));
        asm("" : "+v"(w2[m]));
        asm("" : "+v"(w3[m]));
    }

    float wih0 = wih_pk[0 * 64 + j], wih1 = wih_pk[1 * 64 + j];
    float wih2 = wih_pk[2 * 64 + j], wih3 = wih_pk[3 * 64 + j];
    float bs0 = bias_pk[0 * 64 + j], bs1 = bias_pk[1 * 64 + j];
    float bs2 = bias_pk[2 * 64 + j], bs3 = bias_pk[3 * 64 + j];

    float h = (j < H_) ? h0[b * H_ + j] : 0.0f;
    float c = (j < H_) ? c0[b * H_ + j] : 0.0f;
    hs[j] = h;  // single wave: LDS pipe is in-order per wave, no barrier

    // initial h-pair prefetch (uniform-address b64 reads -> broadcast)
    f32x2 hp[25];
    #pragma unroll
    for (int m = 0; m < 25; ++m)
        hp[m] = *reinterpret_cast<const f32x2*>(&hs[2 * m]);

    const float* __restrict__ xrow = x + b * S_;
    float xt = xrow[0];

    for (int s = 0; s < S_; ++s) {
        int sn = s + 1 < S_ ? s + 1 : S_ - 1;
        float xt_n = xrow[sn];

        // acc.x accumulates even-k, acc.y odd-k; one pk_fma = 2 MACs.
        f32x2 acc0, acc1, acc2, acc3;
        acc0.x = __builtin_fmaf(xt, wih0, bs0); acc0.y = 0.0f;
        acc1.x = __builtin_fmaf(xt, wih1, bs1); acc1.y = 0.0f;
        acc2.x = __builtin_fmaf(xt, wih2, bs2); acc2.y = 0.0f;
        acc3.x = __builtin_fmaf(xt, wih3, bs3); acc3.y = 0.0f;

        #pragma unroll
        for (int m = 0; m < 25; ++m) {
            asm("v_pk_fma_f32 %0, %1, %2, %0" : "+v"(acc0) : "v"(w0[m]), "v"(hp[m]));
            asm("v_pk_fma_f32 %0, %1, %2, %0" : "+v"(acc1) : "v"(w1[m]), "v"(hp[m]));
            asm("v_pk_fma_f32 %0, %1, %2, %0" : "+v"(acc2) : "v"(w2[m]), "v"(hp[m]));
            asm("v_pk_fma_f32 %0, %1, %2, %0" : "+v"(acc3) : "v"(w3[m]), "v"(hp[m]));
        }
        float a0 = acc0.x + acc0.y;  // i gate, arg = -log2e * gate
        float a1 = acc1.x + acc1.y;  // f gate
        float a2 = acc2.x + acc2.y;  // g gate, arg = 2*log2e * gate
        float a3 = acc3.x + acc3.y;  // o gate

        float ei = ex2_(a0); float si = rcp_(1.0f + ei);          // sigmoid(i)
        float ef = ex2_(a1); float sf = rcp_(1.0f + ef);          // sigmoid(f)
        float eg = ex2_(a2);
        float tg = __builtin_fmaf(-2.0f, rcp_(1.0f + eg), 1.0f);  // tanh(g)
        float eo = ex2_(a3); float so = rcp_(1.0f + eo);          // sigmoid(o)

        c = __builtin_fmaf(sf, c, si * tg);
        float ec = ex2_((2.0f * LOG2E) * c);
        float tc = __builtin_fmaf(-2.0f, rcp_(1.0f + ec), 1.0f);  // tanh(c)
        h = so * tc;

        hs[j] = h;  // publish h for next step (in-order LDS, same wave)
        // prefetch next step's h pairs immediately; latency hides under the
        // loop tail + xt fmas (compiler emits incremental lgkmcnt waits).
        #pragma unroll
        for (int m = 0; m < 25; ++m)
            hp[m] = *reinterpret_cast<const f32x2*>(&hs[2 * m]);

        xt = xt_n;
    }

    // outputs: [out (B,1)] [h_n (1,B,H)] [c_n (1,B,H)] concatenated
    if (j < H_) {
        out[B_ + b * H_ + j]            = h;
        out[B_ + B_ * H_ + b * H_ + j]  = c;
    }
    float p = (j < H_) ? h * fc_w[j] : 0.0f;
    #pragma unroll
    for (int off = 32; off > 0; off >>= 1) p += __shfl_xor(p, off);
    if (j == 0) out[b] = p + fc_b[0];
}

extern "C" void kernel_launch(void* const* d_in, const int* in_sizes, int n_in,
                              void* d_out, int out_size, void* d_ws, size_t ws_size,
                              hipStream_t stream)
{
    const float* x    = (const float*)d_in[0];
    const float* h0   = (const float*)d_in[1];
    const float* c0   = (const float*)d_in[2];
    const float* W_ih = (const float*)d_in[3];
    const float* W_hh = (const float*)d_in[4];
    const float* b_ih = (const float*)d_in[5];
    const float* b_hh = (const float*)d_in[6];
    const float* fc_w = (const float*)d_in[7];
    const float* fc_b = (const float*)d_in[8];
    float* out = (float*)d_out;

    f32x2* wf2     = (f32x2*)d_ws;                                  // 6400 f32x2 = 51.2 KB
    float* wih_pk  = (float*)((char*)d_ws + 6400 * 8);              // 256 f32
    float* bias_pk = (float*)((char*)d_ws + 6400 * 8 + 256 * 4);    // 256 f32

    lstm_pack<<<16, 256, 0, stream>>>(W_ih, W_hh, b_ih, b_hh, wf2, wih_pk, bias_pk);
    lstm_main<<<B_, 64, 0, stream>>>(x, h0, c0, fc_w, fc_b, wf2, wih_pk, bias_pk, out);
}

// Round 7
// 198.269 us; speedup vs baseline: 1.0737x; 1.0737x over previous
//
#include <hip/hip_runtime.h>

// LSTM forecast: B=1024, S=512, I=1, H=50.
// 1 wave = 1 batch (1024 waves = 1/SIMD chip-wide). Lane j<50 owns the 4
// gate rows (i,f,g,o) for hidden index j; cell update lane-local.
// R7: (a) NO asm pins (R4 evidence suggests they forced per-step v_mov
// copies); rely on waves_per_eu(1,1)+flat_work_group_size for the register
// budget, f16 weights keep the live set ~140 << 512 so no spill pressure.
// (b) h-broadcast moved off the VALU pipe: even lanes ds_write one f16x2
// pair, all lanes re-read via uniform-address ds_read_b32 (bank broadcast,
// LDS pipe) -- replaces 25 v_readlane (~100 VALU cyc) with ~8 cyc + hidden
// LDS traffic. Matmul stays 100x fdot2 (f16 pairs, 100 weight VGPRs).

typedef _Float16 half2v __attribute__((ext_vector_type(2)));

#define LOG2E 1.44269504088896340736f
#define B_ 1024
#define S_ 512
#define H_ 50

__device__ __forceinline__ float rcp_(float x) { return __builtin_amdgcn_rcpf(x); }
__device__ __forceinline__ float ex2_(float x) { return __builtin_amdgcn_exp2f(x); }

// Pack W_hh into [gate][pair m][lane] f16-pairs, pre-scaled by activation
// log2 factors (i,f,o: -log2e ; g: +2*log2e). Also pre-scale W_ih and biases.
__global__ void lstm_pack(const float* __restrict__ W_ih, const float* __restrict__ W_hh,
                          const float* __restrict__ b_ih, const float* __restrict__ b_hh,
                          unsigned* __restrict__ wpk, float* __restrict__ wih_pk,
                          float* __restrict__ bias_pk)
{
    int tid = blockIdx.x * blockDim.x + threadIdx.x;
    int stride = blockDim.x * gridDim.x;
    for (int p = tid; p < 4 * 25 * 64; p += stride) {
        int j = p & 63;
        int m = (p >> 6) % 25;
        int g = p / (25 * 64);
        float s = (g == 2) ? (2.0f * LOG2E) : (-LOG2E);
        float a = 0.0f, bb = 0.0f;
        if (j < H_) {
            int row = g * H_ + j;
            a  = s * W_hh[row * H_ + 2 * m];
            bb = s * W_hh[row * H_ + 2 * m + 1];
        }
        half2v hv;
        hv.x = (_Float16)a;
        hv.y = (_Float16)bb;
        wpk[p] = __builtin_bit_cast(unsigned, hv);
    }
    for (int p = tid; p < 4 * 64; p += stride) {
        int j = p & 63;
        int g = p >> 6;
        float s = (g == 2) ? (2.0f * LOG2E) : (-LOG2E);
        float wi = 0.0f, bb = 0.0f;
        if (j < H_) {
            int row = g * H_ + j;
            wi = s * W_ih[row];
            bb = s * (b_ih[row] + b_hh[row]);
        }
        wih_pk[p] = wi;
        bias_pk[p] = bb;
    }
}

__global__
__attribute__((amdgpu_flat_work_group_size(64, 64)))
__attribute__((amdgpu_waves_per_eu(1, 1)))
void lstm_main(const float* __restrict__ x, const float* __restrict__ h0,
               const float* __restrict__ c0, const float* __restrict__ fc_w,
               const float* __restrict__ fc_b, const unsigned* __restrict__ wpk,
               const float* __restrict__ wih_pk, const float* __restrict__ bias_pk,
               float* __restrict__ out)
{
    const int b = blockIdx.x;
    const int j = threadIdx.x;

    // f16x2 h-pairs published here; entry m = (h[2m], h[2m+1]).
    __shared__ unsigned hs16[32];

    // Per-lane weights: 4 gates x 25 f16-pairs = 100 VGPRs, coalesced loads.
    half2v w0[25], w1[25], w2[25], w3[25];
    #pragma unroll
    for (int m = 0; m < 25; ++m) {
        w0[m] = __builtin_bit_cast(half2v, wpk[(0 * 25 + m) * 64 + j]);
        w1[m] = __builtin_bit_cast(half2v, wpk[(1 * 25 + m) * 64 + j]);
        w2[m] = __builtin_bit_cast(half2v, wpk[(2 * 25 + m) * 64 + j]);
        w3[m] = __builtin_bit_cast(half2v, wpk[(3 * 25 + m) * 64 + j]);
    }

    float wih0 = wih_pk[0 * 64 + j], wih1 = wih_pk[1 * 64 + j];
    float wih2 = wih_pk[2 * 64 + j], wih3 = wih_pk[3 * 64 + j];
    float bs0 = bias_pk[0 * 64 + j], bs1 = bias_pk[1 * 64 + j];
    float bs2 = bias_pk[2 * 64 + j], bs3 = bias_pk[3 * 64 + j];

    float h = (j < H_) ? h0[b * H_ + j] : 0.0f;
    float c = (j < H_) ? c0[b * H_ + j] : 0.0f;

    // publish initial h pairs: lane 2m packs (h[2m], h[2m+1]) and writes
    // slot m. Single wave per block: LDS is in-order per wave, no barrier.
    {
        int hn_ = __builtin_amdgcn_update_dpp(0, __builtin_bit_cast(int, h),
                                              0xB1, 0xF, 0xF, true);
        unsigned hpk = __builtin_bit_cast(unsigned,
            __builtin_amdgcn_cvt_pkrtz(h, __builtin_bit_cast(float, hn_)));
        if ((j & 1) == 0 && j < H_ + 1) hs16[j >> 1] = hpk;
    }
    unsigned hp[25];
    #pragma unroll
    for (int m = 0; m < 25; ++m) hp[m] = hs16[m];

    const float* __restrict__ xrow = x + b * S_;
    float xt = xrow[0];

    for (int s = 0; s < S_; ++s) {
        int sn = s + 1 < S_ ? s + 1 : S_ - 1;
        float xt_n = xrow[sn];

        float a0 = __builtin_fmaf(xt, wih0, bs0);
        float a1 = __builtin_fmaf(xt, wih1, bs1);
        float a2 = __builtin_fmaf(xt, wih2, bs2);
        float a3 = __builtin_fmaf(xt, wih3, bs3);

        #pragma unroll
        for (int m = 0; m < 25; ++m) {
            half2v hm = __builtin_bit_cast(half2v, hp[m]);
            a0 = __builtin_amdgcn_fdot2(hm, w0[m], a0, false);
            a1 = __builtin_amdgcn_fdot2(hm, w1[m], a1, false);
            a2 = __builtin_amdgcn_fdot2(hm, w2[m], a2, false);
            a3 = __builtin_amdgcn_fdot2(hm, w3[m], a3, false);
        }
        // a0..a3: i,f,g,o gate args, activation scales pre-folded.
        float ei = ex2_(a0); float si = rcp_(1.0f + ei);          // sigmoid(i)
        float ef = ex2_(a1); float sf = rcp_(1.0f + ef);          // sigmoid(f)
        float eg = ex2_(a2);
        float tg = __builtin_fmaf(-2.0f, rcp_(1.0f + eg), 1.0f);  // tanh(g)
        float eo = ex2_(a3); float so = rcp_(1.0f + eo);          // sigmoid(o)

        c = __builtin_fmaf(sf, c, si * tg);
        float ec = ex2_((2.0f * LOG2E) * c);
        float tc = __builtin_fmaf(-2.0f, rcp_(1.0f + ec), 1.0f);  // tanh(c)
        h = so * tc;

        // publish next h pairs (DPP+pkrtz+masked write: ~3 VALU), then
        // re-read the 25 uniform words; LDS latency hides under the loop
        // tail / next step's bias fmas.
        int hn_ = __builtin_amdgcn_update_dpp(0, __builtin_bit_cast(int, h),
                                              0xB1, 0xF, 0xF, true);
        unsigned hpk = __builtin_bit_cast(unsigned,
            __builtin_amdgcn_cvt_pkrtz(h, __builtin_bit_cast(float, hn_)));
        if ((j & 1) == 0 && j < H_ + 1) hs16[j >> 1] = hpk;
        #pragma unroll
        for (int m = 0; m < 25; ++m) hp[m] = hs16[m];

        xt = xt_n;
    }

    // outputs: [out (B,1)] [h_n (1,B,H)] [c_n (1,B,H)] concatenated
    if (j < H_) {
        out[B_ + b * H_ + j]            = h;
        out[B_ + B_ * H_ + b * H_ + j]  = c;
    }
    float p = (j < H_) ? h * fc_w[j] : 0.0f;
    #pragma unroll
    for (int off = 32; off > 0; off >>= 1) p += __shfl_xor(p, off);
    if (j == 0) out[b] = p + fc_b[0];
}

extern "C" void kernel_launch(void* const* d_in, const int* in_sizes, int n_in,
                              void* d_out, int out_size, void* d_ws, size_t ws_size,
                              hipStream_t stream)
{
    const float* x    = (const float*)d_in[0];
    const float* h0   = (const float*)d_in[1];
    const float* c0   = (const float*)d_in[2];
    const float* W_ih = (const float*)d_in[3];
    const float* W_hh = (const float*)d_in[4];
    const float* b_ih = (const float*)d_in[5];
    const float* b_hh = (const float*)d_in[6];
    const float* fc_w = (const float*)d_in[7];
    const float* fc_b = (const float*)d_in[8];
    float* out = (float*)d_out;

    unsigned* wpk  = (unsigned*)d_ws;                               // 6400 u32 = 25.6 KB
    float* wih_pk  = (float*)((char*)d_ws + 6400 * 4);              // 256 f32
    float* bias_pk = (float*)((char*)d_ws + 6400 * 4 + 256 * 4);    // 256 f32

    lstm_pack<<<16, 256, 0, stream>>>(W_ih, W_hh, b_ih, b_hh, wpk, wih_pk, bias_pk);
    lstm_main<<<B_, 64, 0, stream>>>(x, h0, c0, fc_w, fc_b, wpk, wih_pk, bias_pk, out);
}